// Round 3
// baseline (271.808 us; speedup 1.0000x reference)
//
#include <hip/hip_runtime.h>
#include <hip/hip_bf16.h>
#include <math.h>

typedef __bf16 bf16;
typedef __bf16 bf16x4 __attribute__((ext_vector_type(4)));
typedef __bf16 bf16x8 __attribute__((ext_vector_type(8)));
typedef float f32x4 __attribute__((ext_vector_type(4)));
typedef unsigned int u32;
typedef u32 __attribute__((address_space(1))) gu32;
typedef u32 __attribute__((address_space(3))) lu32;

#define TOK   16384
#define D_    256
#define HD    2048
#define VN    2048

#define GLDS16(g, l) __builtin_amdgcn_global_load_lds((gu32*)(g), (lu32*)(l), 16, 0, 0)
// s_waitcnt imm: vmcnt[3:0]|[15:14] | expcnt<<4 | lgkmcnt<<8
#define WAIT_VM(n)  __builtin_amdgcn_s_waitcnt(0x0F70 | (n))   // lgkm=15(no), exp=7(no), vm=n
#define WAIT_LGKM0  __builtin_amdgcn_s_waitcnt(0xC07F)          // vm=63(no), exp=7(no), lgkm=0
#define BAR() do { __builtin_amdgcn_s_barrier(); __builtin_amdgcn_sched_barrier(0); } while (0)

// ---------------------------------------------------------------------------
// prep: roles by blockIdx.x. Dtype flag computed block-locally.
//   b <  4096: convert x
//   b <  4121: biases -> bqkv (WTI-row order), bo -> bob
//   b <  5657: Wq/Wk/Wv transpose into WTI (6144 rows x 256 K):
//              q: row = (d>>4)*256 +       h*16 + (d&15)   (d-block interleave)
//              k: row = (d>>4)*256 + 128 + h*16 + (d&15)
//              v: row = 4096 + d*8 + h                     (d-major)
//   b <  6169: Wo transpose (K permuted d-major) -> WoT
// ---------------------------------------------------------------------------
__device__ __forceinline__ void transpose_body(
    const void* __restrict__ src, bf16* __restrict__ dst, int R, int C,
    int tc, int tr, int f, int mode, float (*tile)[33])
{
    int lx = threadIdx.x & 31, ly = threadIdx.x >> 5;
    for (int i = 0; i < 4; i++) {
        int r = ly + i * 8;
        size_t idx = (size_t)(tr + r) * C + tc + lx;
        tile[r][lx] = f ? ((const float*)src)[idx] : (float)((const bf16*)src)[idx];
    }
    __syncthreads();
    for (int i = 0; i < 4; i++) {
        int r = ly + i * 8;
        int k = tr + lx;                     // source row = K index
        int n = tc + r;                      // source col = output row
        size_t di;
        if (mode == 1)
            di = (size_t)n * 2048 + ((k & 255) << 3) + (k >> 8);
        else if (mode == 2)
            di = (size_t)(4096 + ((n & 255) << 3) + (n >> 8)) * 256 + k;
        else if (mode == 3)
            di = (size_t)((((n & 255) >> 4) << 8) + ((n >> 8) << 4) + (n & 15)) * 256 + k;
        else if (mode == 4)
            di = (size_t)((((n & 255) >> 4) << 8) + 128 + ((n >> 8) << 4) + (n & 15)) * 256 + k;
        else
            di = (size_t)n * R + k;
        dst[di] = (bf16)tile[lx][r];
    }
}

__global__ __launch_bounds__(256) void prep(
    const void* __restrict__ x,
    const void* __restrict__ Wq, const void* __restrict__ bq,
    const void* __restrict__ Wk, const void* __restrict__ bk,
    const void* __restrict__ Wv, const void* __restrict__ bv,
    const void* __restrict__ Wo, const void* __restrict__ bo,
    bf16* __restrict__ xb, bf16* __restrict__ WTI, bf16* __restrict__ WoT,
    bf16* __restrict__ bqkv, bf16* __restrict__ bob)
{
    __shared__ float tile[32][33];
    __shared__ int sflag;
    int tid = threadIdx.x;
    if (tid == 0) sflag = 0;
    __syncthreads();
    {
        float v = fabsf((float)((const bf16*)x)[2 * tid]);
        if (!(v < 1e4f)) sflag = 1;   // benign race, all writers store 1
    }
    __syncthreads();
    int f = sflag;
    int b = blockIdx.x;

    if (b < 4096) {                               // convert x
        int i = b * 256 + tid;
        bf16x4 o;
        if (f) { f32x4 v = ((const f32x4*)x)[i]; for (int e = 0; e < 4; e++) o[e] = (bf16)v[e]; }
        else   { o = ((const bf16x4*)x)[i]; }
        ((bf16x4*)xb)[i] = o;
    } else if (b < 4121) {                        // biases (WTI-row order)
        int i = (b - 4096) * 256 + tid;
        if (i < 6400) {
            const void* src; bf16* dst = bqkv; int off, woff;
            if (i < 2048) {
                src = bq; off = i;
                int d = off & 255, h = off >> 8;
                woff = ((d >> 4) << 8) + (h << 4) + (d & 15);
            } else if (i < 4096) {
                src = bk; off = i - 2048;
                int d = off & 255, h = off >> 8;
                woff = ((d >> 4) << 8) + 128 + (h << 4) + (d & 15);
            } else if (i < 6144) {
                src = bv; off = i - 4096;
                woff = 4096 + ((off & 255) << 3) + (off >> 8);
            } else {
                src = bo; dst = bob; off = i - 6144; woff = off;
            }
            float v = f ? ((const float*)src)[off] : (float)((const bf16*)src)[off];
            dst[woff] = (bf16)v;
        }
        __syncthreads();                          // match transpose barrier count
    } else if (b < 5657) {                        // Wq/Wk/Wv -> WTI
        int idx = b - 4121;                       // 0..1535
        int tx = idx & 63, rest = idx >> 6;
        int ty = rest & 7, tz = rest >> 3;
        const void* src = (tz == 0) ? Wq : (tz == 1) ? Wk : Wv;
        int mode = (tz == 0) ? 3 : (tz == 1) ? 4 : 2;
        transpose_body(src, WTI, 256, 2048, tx * 32, ty * 32, f, mode, tile);
    } else {                                      // Wo -> WoT (K d-major)
        int idx = b - 5657;                       // 0..511
        int tx = idx & 7, ty = idx >> 3;
        transpose_body(Wo, WoT, 2048, 256, tx * 32, ty * 32, f, 1, tile);
    }
}

// ---------------------------------------------------------------------------
// Kernel 1: fused qkv-projection + per-token 8x8 softmax.
// Per block: 64 tokens. A (x-tile) staged once then held in registers
// (16 bf16x8/lane). N swept as 96 64-col subtiles of WTI: 64 q/k subtiles
// (d-block interleaved) whose outputs stay in LDS (qkh) and feed the score
// accumulators; 32 v subtiles written to HBM (d-major). P written at end.
// q,k NEVER touch HBM. Double-buffered Ws + counted vmcnt + raw barriers.
// HBM: read x 8 MB + WTI (L2-resident); write v 67 MB + P 4 MB.
// ---------------------------------------------------------------------------
__global__ __launch_bounds__(512, 2) void qkv_score(
    const bf16* __restrict__ X, const bf16* __restrict__ WTI,
    const bf16* __restrict__ bI, bf16* __restrict__ vout, float* __restrict__ P)
{
    __shared__ bf16 Ws[2][64 * 256];   // 64 KB (W subtile double buffer; [0] also x-tile at prologue)
    __shared__ bf16 qkh[64 * 256];     // 32 KB ([t][qk*128+h*16+dd] XOR-swz; v-epi staging)
    int tid = threadIdx.x, wave = tid >> 6, lane = tid & 63;
    int mrow = lane & 15, quad = lane >> 4;
    int wm3 = (wave >> 2) * 32, wn3 = (wave & 3) * 16;
    int h = lane >> 3, g = lane & 7;
    int t0 = blockIdx.x * 64;

    // ---- prologue: stage x-tile into Ws[0], lift A into registers ----
#pragma unroll
    for (int i = 0; i < 4; i++) {
        int row = (i * 8 + wave) * 2 + (lane >> 5);
        int sl = lane & 31;
        int gc = (sl & 24) | ((sl & 7) ^ (row & 7));
        GLDS16(&X[(size_t)(t0 + row) * 256 + gc * 8], &Ws[0][(i * 8 + wave) * 512]);
    }
    WAIT_VM(0);
    BAR();
    bf16x8 areg[2][8];
#pragma unroll
    for (int mt = 0; mt < 2; mt++)
#pragma unroll
        for (int ks = 0; ks < 8; ks++) {
            int arow = wm3 + mt * 16 + mrow;
            int sl = ks * 4 + quad;
            int ph = (sl & 24) | ((sl & 7) ^ (arow & 7));
            areg[mt][ks] = *(const bf16x8*)&Ws[0][arow * 256 + ph * 8];
        }
    WAIT_LGKM0;                    // A reads done before Ws[0] restage
    BAR();

    // stage subtile 0
#pragma unroll
    for (int i = 0; i < 4; i++) {
        int row = (i * 8 + wave) * 2 + (lane >> 5);
        int sl = lane & 31;
        int gc = (sl & 24) | ((sl & 7) ^ (row & 7));
        GLDS16(&WTI[(size_t)row * 256 + gc * 8], &Ws[0][(i * 8 + wave) * 512]);
    }

    float S[8] = {};

    for (int s = 0; s < 96; s++) {
        int cur = s & 1;
        if (s < 95) {              // stage subtile s+1 (in flight across compute)
#pragma unroll
            for (int i = 0; i < 4; i++) {
                int row = (i * 8 + wave) * 2 + (lane >> 5);
                int sl = lane & 31;
                int gc = (sl & 24) | ((sl & 7) ^ (row & 7));
                GLDS16(&WTI[(size_t)((s + 1) * 64 + row) * 256 + gc * 8],
                       &Ws[cur ^ 1][(i * 8 + wave) * 512]);
            }
            WAIT_VM(4);            // subtile s resident; s+1's 4 in flight
        } else {
            WAIT_VM(0);
        }
        BAR();                     // all waves see Ws[cur]

        // GEMM: this wave -> rows wm3..+31 (2 frags), cols wn3..+15
        f32x4 acc0 = {}, acc1 = {};
        int brow = wn3 + mrow;
#pragma unroll
        for (int ks = 0; ks < 8; ks++) {
            int sl = ks * 4 + quad;
            int ph = (sl & 24) | ((sl & 7) ^ (brow & 7));
            bf16x8 bv = *(const bf16x8*)&Ws[cur][brow * 256 + ph * 8];
            acc0 = __builtin_amdgcn_mfma_f32_16x16x32_bf16(bv, areg[0][ks], acc0, 0, 0, 0);
            acc1 = __builtin_amdgcn_mfma_f32_16x16x32_bf16(bv, areg[1][ks], acc1, 0, 0, 0);
        }

        if (s < 64) {
            // q/k epilogue -> qkh (bias added, XOR-swizzled by token)
            int sub = s & 3, qk = sub >> 1;
            int hh = (sub & 1) * 4 + (wn3 >> 4);
            bf16x4 bb = *(const bf16x4*)&bI[s * 64 + wn3 + quad * 4];
#pragma unroll
            for (int mt = 0; mt < 2; mt++) {
                int t = wm3 + mt * 16 + mrow;
                f32x4 a = mt ? acc1 : acc0;
                bf16x4 o;
#pragma unroll
                for (int r = 0; r < 4; r++) o[r] = (bf16)(a[r] + (float)bb[r]);
                int bo = ((qk << 8) + (hh << 5) + (quad << 3)) ^ ((t & 7) << 4);
                *(bf16x4*)((char*)qkh + t * 512 + bo) = o;
            }
            WAIT_LGKM0;            // epi writes committed before barrier
            BAR();
            if ((s & 3) == 3) {
                // score accumulate, d-block j = s>>2: wave owns tokens wave*8..+7
#pragma unroll
                for (int ti = 0; ti < 8; ti++) {
                    int t = wave * 8 + ti;
                    int swz = (t & 7) << 4;
                    const char* base = (const char*)qkh + t * 512;
                    bf16x8 q0 = *(const bf16x8*)(base + (((h << 5)) ^ swz));
                    bf16x8 q1 = *(const bf16x8*)(base + (((h << 5) + 16) ^ swz));
                    bf16x8 k0 = *(const bf16x8*)(base + ((256 + (g << 5)) ^ swz));
                    bf16x8 k1 = *(const bf16x8*)(base + ((256 + (g << 5) + 16) ^ swz));
                    float a = 0.f;
#pragma unroll
                    for (int e = 0; e < 8; e++)
                        a += (float)q0[e] * (float)k0[e] + (float)q1[e] * (float)k1[e];
                    S[ti] += a;
                }
                WAIT_LGKM0;        // score reads done before qkh rewritten
            }
        } else {
            // v epilogue: stage ep[64][72] in qkh, then coalesced HBM store
            int sv = s - 64;
            bf16* ep = qkh;
            bf16x4 bb = *(const bf16x4*)&bI[s * 64 + wn3 + quad * 4];
#pragma unroll
            for (int mt = 0; mt < 2; mt++) {
                int t = wm3 + mt * 16 + mrow;
                f32x4 a = mt ? acc1 : acc0;
                bf16x4 o;
#pragma unroll
                for (int r = 0; r < 4; r++) o[r] = (bf16)(a[r] + (float)bb[r]);
                *(bf16x4*)&ep[t * 72 + wn3 + quad * 4] = o;
            }
            WAIT_LGKM0;
            BAR();                 // ep complete
            {
                int tt = tid >> 3, c8 = (tid & 7) * 8;
                bf16x8 val = *(const bf16x8*)&ep[tt * 72 + c8];
                *(bf16x8*)&vout[(size_t)(t0 + tt) * VN + sv * 64 + c8] = val;
            }
            BAR();                 // end-of-iter (protects ep reuse)
        }
    }

    // ---- softmax + P write (wave owns tokens wave*8..+7) ----
#pragma unroll
    for (int ti = 0; ti < 8; ti++) {
        int t = t0 + wave * 8 + ti;
        float sc = S[ti] * 0.0625f;
        float m = sc;
        for (int off = 1; off < 8; off <<= 1) m = fmaxf(m, __shfl_xor(m, off, 8));
        float p = __expf(sc - m);
        float sum = p;
        for (int off = 1; off < 8; off <<= 1) sum += __shfl_xor(sum, off, 8);
        P[(size_t)t * 64 + lane] = p / sum;
    }
}

// ---------------------------------------------------------------------------
// Kernel 2: out = (P @ v) @ Wo' + bo, attnout never in LDS or HBM.
// (Verified round-2 kernel; only change: v is now a dedicated d-major buffer
// vbuf[t][d*8+g], stride 2048, no +4096 offset.)
// ---------------------------------------------------------------------------
__global__ __launch_bounds__(256) void out_fused(
    const bf16* __restrict__ vb, const bf16* __restrict__ WoT,
    const float* __restrict__ P, const bf16* __restrict__ bob,
    float* __restrict__ outp)
{
    __shared__ bf16 Bs[2][256 * 64];   // 64 KB  Wo' chunk (double)
    __shared__ bf16 Vs[2][32 * 64];    // 8 KB   v chunk (double)
    int m0 = blockIdx.x * 32;
    int tid = threadIdx.x, wave = tid >> 6, lane = tid & 63;
    int wm = (wave >> 1) * 16, wn = (wave & 1) * 128;
    int mrow = lane & 15, quad = lane >> 4;
    int t = wm + mrow, ts = t & 7;
    int sl8 = lane >> 3, sl = lane & 7;

    float Pv[64];
    {
        const float* pr = P + (size_t)(m0 + t) * 64;
#pragma unroll
        for (int j = 0; j < 16; j++) {
            f32x4 v4 = *(const f32x4*)&pr[j * 4];
            Pv[4 * j + 0] = v4[0]; Pv[4 * j + 1] = v4[1];
            Pv[4 * j + 2] = v4[2]; Pv[4 * j + 3] = v4[3];
        }
    }

    f32x4 acc[8] = {};
    {   // prologue: stage chunk 0
        int tt = (wave << 3) + sl8;
        GLDS16(&vb[(size_t)(m0 + tt) * VN + ((sl ^ (tt & 7)) << 3)],
               &Vs[0][wave * 512]);
#pragma unroll
        for (int i = 0; i < 8; i++) {
            int n = (wave << 6) + (i << 3) + sl8;
            GLDS16(&WoT[(size_t)n * HD + ((sl ^ (n & 7)) << 3)],
                   &Bs[0][((wave << 6) + (i << 3)) << 6]);
        }
    }

    for (int c = 0; c < 32; c++) {
        __syncthreads();               // buf[c&1] resident (barrier drains vmcnt)
        if (c < 31) {
            int cc = c + 1, bb = cc & 1;
            int tt = (wave << 3) + sl8;
            GLDS16(&vb[(size_t)(m0 + tt) * VN + cc * 64 + ((sl ^ (tt & 7)) << 3)],
                   &Vs[bb][wave * 512]);
#pragma unroll
            for (int i = 0; i < 8; i++) {
                int n = (wave << 6) + (i << 3) + sl8;
                GLDS16(&WoT[(size_t)n * HD + cc * 64 + ((sl ^ (n & 7)) << 3)],
                       &Bs[bb][((wave << 6) + (i << 3)) << 6]);
            }
        }
        const bf16* Vb = Vs[c & 1];
        const bf16* Bb = Bs[c & 1];

        bf16x8 vf0 = *(const bf16x8*)&Vb[(t << 6) + ((quad ^ ts) << 3)];
        bf16x8 vf1 = *(const bf16x8*)&Vb[(t << 6) + (((quad + 4) ^ ts) << 3)];
        float v0f[8], v1f[8];
#pragma unroll
        for (int e = 0; e < 8; e++) { v0f[e] = (float)vf0[e]; v1f[e] = (float)vf1[e]; }
        bf16x8 af0, af1;
#pragma unroll
        for (int hh = 0; hh < 8; hh++) {
            float a0 = 0.f, a1 = 0.f;
#pragma unroll
            for (int gg = 0; gg < 8; gg++) {
                a0 += Pv[hh * 8 + gg] * v0f[gg];
                a1 += Pv[hh * 8 + gg] * v1f[gg];
            }
            af0[hh] = (bf16)a0; af1[hh] = (bf16)a1;
        }
#pragma unroll
        for (int nt = 0; nt < 8; nt++) {
            bf16x8 bv = *(const bf16x8*)&Bb[(wn + nt * 16 + mrow) * 64
                            + ((quad ^ (mrow & 7)) << 3)];
            acc[nt] = __builtin_amdgcn_mfma_f32_16x16x32_bf16(bv, af0, acc[nt], 0, 0, 0);
        }
#pragma unroll
        for (int nt = 0; nt < 8; nt++) {
            bf16x8 bv = *(const bf16x8*)&Bb[(wn + nt * 16 + mrow) * 64
                            + (((4 + quad) ^ (mrow & 7)) << 3)];
            acc[nt] = __builtin_amdgcn_mfma_f32_16x16x32_bf16(bv, af1, acc[nt], 0, 0, 0);
        }
    }

    int row = m0 + wm + mrow;
#pragma unroll
    for (int nt = 0; nt < 8; nt++) {
        int col = wn + nt * 16 + quad * 4;
        bf16x4 bb = *(const bf16x4*)&bob[col];
        f32x4 o;
        for (int r = 0; r < 4; r++) o[r] = acc[nt][r] + (float)bb[r];
        *(f32x4*)&outp[(size_t)row * D_ + col] = o;
    }
}

// ---------------------------------------------------------------------------
extern "C" void kernel_launch(void* const* d_in, const int* in_sizes, int n_in,
                              void* d_out, int out_size, void* d_ws, size_t ws_size,
                              hipStream_t stream)
{
    const void* x  = d_in[0];
    const void* Wq = d_in[1];
    const void* bq = d_in[2];
    const void* Wk = d_in[3];
    const void* bk = d_in[4];
    const void* Wv = d_in[5];
    const void* bv = d_in[6];
    const void* Wo = d_in[7];
    const void* bo = d_in[8];
    float* out = (float*)d_out;

    char* ws = (char*)d_ws;
    bf16*  vbuf = (bf16*)ws;                      // 16384*2048*2 = 67108864
    bf16*  WTI  = (bf16*)(ws + 67108864);         // 6144*256*2   = 3145728
    bf16*  WoT  = (bf16*)(ws + 70254592);         // 256*2048*2   = 1048576
    bf16*  xb   = (bf16*)(ws + 71303168);         // 16384*256*2  = 8388608
    bf16*  bqkv = (bf16*)(ws + 79691776);         // 6144*2       = 12288
    bf16*  bob  = (bf16*)(ws + 79704064);         // 512
    float* Pbuf = (float*)(ws + 79704576);        // 16384*64*4   = 4194304

    prep<<<6169, 256, 0, stream>>>(x, Wq, bq, Wk, bk, Wv, bv, Wo, bo,
                                   xb, WTI, WoT, bqkv, bob);
    qkv_score<<<256, 512, 0, stream>>>(xb, WTI, bqkv, vbuf, Pbuf);
    out_fused<<<512, 256, 0, stream>>>(vbuf, WoT, Pbuf, bob, out);
}

// Round 5
// 270.319 us; speedup vs baseline: 1.0055x; 1.0055x over previous
//
#include <hip/hip_runtime.h>
#include <hip/hip_bf16.h>
#include <math.h>

typedef __bf16 bf16;
typedef __bf16 bf16x4 __attribute__((ext_vector_type(4)));
typedef __bf16 bf16x8 __attribute__((ext_vector_type(8)));
typedef float f32x4 __attribute__((ext_vector_type(4)));
typedef unsigned int u32;
typedef u32 __attribute__((address_space(1))) gu32;
typedef u32 __attribute__((address_space(3))) lu32;

#define TOK   16384
#define D_    256
#define HD    2048
#define VN    2048

#define GLDS16(g, l) __builtin_amdgcn_global_load_lds((gu32*)(g), (lu32*)(l), 16, 0, 0)
// s_waitcnt imm: vmcnt[3:0]|[15:14] | expcnt<<4 | lgkmcnt<<8
#define WAIT_VM(n)  __builtin_amdgcn_s_waitcnt(0x0F70 | (n))   // lgkm=15(no), exp=7(no), vm=n (LITERAL only)
#define WAIT_LGKM0  __builtin_amdgcn_s_waitcnt(0xC07F)          // vm=63(no), exp=7(no), lgkm=0
#define BAR() do { __builtin_amdgcn_s_barrier(); __builtin_amdgcn_sched_barrier(0); } while (0)

// ---------------------------------------------------------------------------
// prep: roles by blockIdx.x. Dtype flag computed block-locally.  (unchanged)
//   b <  4096: convert x
//   b <  4121: biases -> bqkv (WTI-row order), bo -> bob
//   b <  5657: Wq/Wk/Wv transpose into WTI (6144 rows x 256 K):
//              q: row = (d>>4)*256 +       h*16 + (d&15)   (d-block interleave)
//              k: row = (d>>4)*256 + 128 + h*16 + (d&15)
//              v: row = 4096 + d*8 + h                     (d-major)
//   b <  6169: Wo transpose (K permuted d-major) -> WoT
// ---------------------------------------------------------------------------
__device__ __forceinline__ void transpose_body(
    const void* __restrict__ src, bf16* __restrict__ dst, int R, int C,
    int tc, int tr, int f, int mode, float (*tile)[33])
{
    int lx = threadIdx.x & 31, ly = threadIdx.x >> 5;
    for (int i = 0; i < 4; i++) {
        int r = ly + i * 8;
        size_t idx = (size_t)(tr + r) * C + tc + lx;
        tile[r][lx] = f ? ((const float*)src)[idx] : (float)((const bf16*)src)[idx];
    }
    __syncthreads();
    for (int i = 0; i < 4; i++) {
        int r = ly + i * 8;
        int k = tr + lx;                     // source row = K index
        int n = tc + r;                      // source col = output row
        size_t di;
        if (mode == 1)
            di = (size_t)n * 2048 + ((k & 255) << 3) + (k >> 8);
        else if (mode == 2)
            di = (size_t)(4096 + ((n & 255) << 3) + (n >> 8)) * 256 + k;
        else if (mode == 3)
            di = (size_t)((((n & 255) >> 4) << 8) + ((n >> 8) << 4) + (n & 15)) * 256 + k;
        else if (mode == 4)
            di = (size_t)((((n & 255) >> 4) << 8) + 128 + ((n >> 8) << 4) + (n & 15)) * 256 + k;
        else
            di = (size_t)n * R + k;
        dst[di] = (bf16)tile[lx][r];
    }
}

__global__ __launch_bounds__(256) void prep(
    const void* __restrict__ x,
    const void* __restrict__ Wq, const void* __restrict__ bq,
    const void* __restrict__ Wk, const void* __restrict__ bk,
    const void* __restrict__ Wv, const void* __restrict__ bv,
    const void* __restrict__ Wo, const void* __restrict__ bo,
    bf16* __restrict__ xb, bf16* __restrict__ WTI, bf16* __restrict__ WoT,
    bf16* __restrict__ bqkv, bf16* __restrict__ bob)
{
    __shared__ float tile[32][33];
    __shared__ int sflag;
    int tid = threadIdx.x;
    if (tid == 0) sflag = 0;
    __syncthreads();
    {
        float v = fabsf((float)((const bf16*)x)[2 * tid]);
        if (!(v < 1e4f)) sflag = 1;   // benign race, all writers store 1
    }
    __syncthreads();
    int f = sflag;
    int b = blockIdx.x;

    if (b < 4096) {                               // convert x
        int i = b * 256 + tid;
        bf16x4 o;
        if (f) { f32x4 v = ((const f32x4*)x)[i]; for (int e = 0; e < 4; e++) o[e] = (bf16)v[e]; }
        else   { o = ((const bf16x4*)x)[i]; }
        ((bf16x4*)xb)[i] = o;
    } else if (b < 4121) {                        // biases (WTI-row order)
        int i = (b - 4096) * 256 + tid;
        if (i < 6400) {
            const void* src; bf16* dst = bqkv; int off, woff;
            if (i < 2048) {
                src = bq; off = i;
                int d = off & 255, h = off >> 8;
                woff = ((d >> 4) << 8) + (h << 4) + (d & 15);
            } else if (i < 4096) {
                src = bk; off = i - 2048;
                int d = off & 255, h = off >> 8;
                woff = ((d >> 4) << 8) + 128 + (h << 4) + (d & 15);
            } else if (i < 6144) {
                src = bv; off = i - 4096;
                woff = 4096 + ((off & 255) << 3) + (off >> 8);
            } else {
                src = bo; dst = bob; off = i - 6144; woff = off;
            }
            float v = f ? ((const float*)src)[off] : (float)((const bf16*)src)[off];
            dst[woff] = (bf16)v;
        }
        __syncthreads();                          // match transpose barrier count
    } else if (b < 5657) {                        // Wq/Wk/Wv -> WTI
        int idx = b - 4121;                       // 0..1535
        int tx = idx & 63, rest = idx >> 6;
        int ty = rest & 7, tz = rest >> 3;
        const void* src = (tz == 0) ? Wq : (tz == 1) ? Wk : Wv;
        int mode = (tz == 0) ? 3 : (tz == 1) ? 4 : 2;
        transpose_body(src, WTI, 256, 2048, tx * 32, ty * 32, f, mode, tile);
    } else {                                      // Wo -> WoT (K d-major)
        int idx = b - 5657;                       // 0..511
        int tx = idx & 7, ty = idx >> 3;
        transpose_body(Wo, WoT, 2048, 256, tx * 32, ty * 32, f, 1, tile);
    }
}

// ---------------------------------------------------------------------------
// Kernel 1: v = x @ Wv + bv  (d-major cols). Byte-clone of the verified
// proj_gemm at N=2048: 128x128 tile, 36 KB LDS, 4 blocks/CU, grid (16,128).
// ---------------------------------------------------------------------------
__global__ __launch_bounds__(256) void v_proj(
    const bf16* __restrict__ X, const bf16* __restrict__ WT,
    const bf16* __restrict__ bI, bf16* __restrict__ vout)
{
    __shared__ char smem[36864];               // union: As+Bs (32K) / epi (36K)
    bf16* As = (bf16*)smem;                    // 128*64
    bf16* Bs = (bf16*)(smem + 16384);          // 128*64
    int m0 = blockIdx.y * 128, n0 = blockIdx.x * 128;
    int tid = threadIdx.x, wave = tid >> 6, lane = tid & 63;
    int wm = (wave >> 1) * 64, wn = (wave & 1) * 64;
    int mrow = lane & 15, quad = lane >> 4;
    int lrow8 = lane >> 3, lslot = lane & 7;

    f32x4 acc[4][4] = {};
    for (int k0 = 0; k0 < D_; k0 += 64) {
        __syncthreads();
        for (int i = 0; i < 4; i++) {
            int rbase = wave * 32 + i * 8;
            int row = rbase + lrow8;
            int gc = lslot ^ (row & 7);
            GLDS16(&X[(size_t)(m0 + row) * D_ + k0 + gc * 8], &As[rbase * 64]);
            GLDS16(&WT[(size_t)(n0 + row) * D_ + k0 + gc * 8], &Bs[rbase * 64]);
        }
        __syncthreads();
        for (int kk = 0; kk < 64; kk += 32) {
            int slot = (((kk >> 3) + quad) ^ (mrow & 7)) * 8;
            bf16x8 af[4], bfv[4];
            for (int mt = 0; mt < 4; mt++)
                af[mt] = *(const bf16x8*)&As[(wm + mt * 16 + mrow) * 64 + slot];
            for (int nt = 0; nt < 4; nt++)
                bfv[nt] = *(const bf16x8*)&Bs[(wn + nt * 16 + mrow) * 64 + slot];
            for (int mt = 0; mt < 4; mt++)
                for (int nt = 0; nt < 4; nt++)
                    acc[mt][nt] = __builtin_amdgcn_mfma_f32_16x16x32_bf16(
                        bfv[nt], af[mt], acc[mt][nt], 0, 0, 0);
        }
    }

    __syncthreads();
    bf16* ep = (bf16*)smem + wave * (64 * 72);
    for (int mt = 0; mt < 4; mt++) {
        for (int nt = 0; nt < 4; nt++) {
            int col = n0 + wn + nt * 16 + quad * 4;
            bf16x4 bb = *(const bf16x4*)&bI[col];
            bf16x4 o;
            for (int r = 0; r < 4; r++) o[r] = (bf16)(acc[mt][nt][r] + (float)bb[r]);
            *(bf16x4*)&ep[(mt * 16 + mrow) * 72 + nt * 16 + quad * 4] = o;
        }
    }
    __syncthreads();
    for (int i = 0; i < 8; i++) {
        int r = i * 8 + (lane >> 3);
        int cb = (lane & 7) * 8;
        bf16x8 val = *(const bf16x8*)&ep[r * 72 + cb];
        *(bf16x8*)&vout[(size_t)(m0 + wm + r) * VN + n0 + wn + cb] = val;
    }
}

// ---------------------------------------------------------------------------
// Kernel 2: q/k projection + per-token 8x8 scores + softmax -> P. q,k never
// touch HBM. Round-3 arithmetic/layout verbatim; sync skeleton rebuilt:
//  - Ws TRIPLE buffer (96 KB): stage 2 subtiles ahead, issued AFTER the
//    barrier (buffer (s+2)%3 provably free: its readers retired pre-barrier)
//  - WAIT_VM(4) completes exactly subtile s (ledger: 8 outstanding -> 4)
//  - ONE barrier/iter; epi lgkm-drain+barrier only at d-block end (s%4==3),
//    where the cross-wave score read actually requires it
//  64 iterations (N=4096 q/k cols), 16 MFMA/wave/iter.
// ---------------------------------------------------------------------------
__global__ __launch_bounds__(512, 2) void qk_score(
    const bf16* __restrict__ X, const bf16* __restrict__ WTI,
    const bf16* __restrict__ bI, float* __restrict__ P)
{
    __shared__ bf16 Ws[3][64 * 256];   // 96 KB triple buffer ([2] = x-tile at prologue)
    __shared__ bf16 qkh[64 * 256];     // 32 KB  [t][qk*128+h*16+dd], XOR-swizzled
    int tid = threadIdx.x, wave = tid >> 6, lane = tid & 63;
    int mrow = lane & 15, quad = lane >> 4;
    int wm3 = (wave >> 2) * 32, wn3 = (wave & 3) * 16;
    int h = lane >> 3, g = lane & 7;
    int t0 = blockIdx.x * 64;

    // ---- prologue ----
#pragma unroll
    for (int i = 0; i < 4; i++) {      // x-tile -> Ws[2]
        int row = (i * 8 + wave) * 2 + (lane >> 5);
        int sl = lane & 31;
        int gc = (sl & 24) | ((sl & 7) ^ (row & 7));
        GLDS16(&X[(size_t)(t0 + row) * 256 + gc * 8], &Ws[2][(i * 8 + wave) * 512]);
    }
    WAIT_VM(0);
    BAR();
#pragma unroll
    for (int i = 0; i < 4; i++) {      // stage s=0 -> Ws[0]
        int row = (i * 8 + wave) * 2 + (lane >> 5);
        int sl = lane & 31;
        int gc = (sl & 24) | ((sl & 7) ^ (row & 7));
        GLDS16(&WTI[(size_t)row * 256 + gc * 8], &Ws[0][(i * 8 + wave) * 512]);
    }
#pragma unroll
    for (int i = 0; i < 4; i++) {      // stage s=1 -> Ws[1]
        int row = (i * 8 + wave) * 2 + (lane >> 5);
        int sl = lane & 31;
        int gc = (sl & 24) | ((sl & 7) ^ (row & 7));
        GLDS16(&WTI[(size_t)(64 + row) * 256 + gc * 8], &Ws[1][(i * 8 + wave) * 512]);
    }
    bf16x8 areg[2][8];                 // lift A from Ws[2] (overlaps stages)
#pragma unroll
    for (int mt = 0; mt < 2; mt++)
#pragma unroll
        for (int ks = 0; ks < 8; ks++) {
            int arow = wm3 + mt * 16 + mrow;
            int sl = ks * 4 + quad;
            int ph = (sl & 24) | ((sl & 7) ^ (arow & 7));
            areg[mt][ks] = *(const bf16x8*)&Ws[2][arow * 256 + ph * 8];
        }
    WAIT_LGKM0;                        // all waves' A reads retired
    BAR();                             // before Ws[2] is restaged (at s=0)

    float S[8] = {};

    for (int s = 0; s < 64; s++) {
        int cur = s % 3;
        if (s == 63) { WAIT_VM(0); } else { WAIT_VM(4); }  // subtile s resident
        BAR();                         // published to all waves
        if (s <= 61) {                 // stage s+2 (buffer provably free)
            int nb = (s + 2) % 3;
#pragma unroll
            for (int i = 0; i < 4; i++) {
                int row = (i * 8 + wave) * 2 + (lane >> 5);
                int sl = lane & 31;
                int gc = (sl & 24) | ((sl & 7) ^ (row & 7));
                GLDS16(&WTI[(size_t)((s + 2) * 64 + row) * 256 + gc * 8],
                       &Ws[nb][(i * 8 + wave) * 512]);
            }
        }

        // GEMM: wave -> rows wm3..+31 (2 frags), cols wn3..+15
        int brow = wn3 + mrow;
        bf16x8 bv[8];
#pragma unroll
        for (int ks = 0; ks < 8; ks++) {
            int sl = ks * 4 + quad;
            int ph = (sl & 24) | ((sl & 7) ^ (brow & 7));
            bv[ks] = *(const bf16x8*)&Ws[cur][brow * 256 + ph * 8];
        }
        f32x4 acc0 = {}, acc1 = {};
#pragma unroll
        for (int ks = 0; ks < 8; ks++) {
            acc0 = __builtin_amdgcn_mfma_f32_16x16x32_bf16(bv[ks], areg[0][ks], acc0, 0, 0, 0);
            acc1 = __builtin_amdgcn_mfma_f32_16x16x32_bf16(bv[ks], areg[1][ks], acc1, 0, 0, 0);
        }

        // q/k epilogue -> qkh (bias added, XOR-swizzled by token). Subtiles of
        // one d-block write disjoint bytes: no sync until the score read.
        int sub = s & 3, qk = sub >> 1;
        int hh = (sub & 1) * 4 + (wn3 >> 4);
        bf16x4 bb = *(const bf16x4*)&bI[s * 64 + wn3 + quad * 4];
#pragma unroll
        for (int mt = 0; mt < 2; mt++) {
            int t = wm3 + mt * 16 + mrow;
            f32x4 a = mt ? acc1 : acc0;
            bf16x4 o;
#pragma unroll
            for (int r = 0; r < 4; r++) o[r] = (bf16)(a[r] + (float)bb[r]);
            int bo = ((qk << 8) + (hh << 5) + (quad << 3)) ^ ((t & 7) << 4);
            *(bf16x4*)((char*)qkh + t * 512 + bo) = o;
        }

        if ((s & 3) == 3) {            // d-block complete: accumulate scores
            WAIT_LGKM0;                // my epi writes committed
            BAR();                     // everyone's epi writes visible
#pragma unroll
            for (int ti = 0; ti < 8; ti++) {
                int t = wave * 8 + ti;
                int swz = (t & 7) << 4;
                const char* base = (const char*)qkh + t * 512;
                bf16x8 q0 = *(const bf16x8*)(base + (((h << 5)) ^ swz));
                bf16x8 q1 = *(const bf16x8*)(base + (((h << 5) + 16) ^ swz));
                bf16x8 k0 = *(const bf16x8*)(base + ((256 + (g << 5)) ^ swz));
                bf16x8 k1 = *(const bf16x8*)(base + ((256 + (g << 5) + 16) ^ swz));
                float a = 0.f;
#pragma unroll
                for (int e = 0; e < 8; e++)
                    a += (float)q0[e] * (float)k0[e] + (float)q1[e] * (float)k1[e];
                S[ti] += a;
            }
            WAIT_LGKM0;                // my score reads retired before next
        }                              // d-block's writers pass their barrier
    }

    // ---- softmax + P write (wave owns tokens wave*8..+7) ----
#pragma unroll
    for (int ti = 0; ti < 8; ti++) {
        int t = t0 + wave * 8 + ti;
        float sc = S[ti] * 0.0625f;
        float m = sc;
        for (int off = 1; off < 8; off <<= 1) m = fmaxf(m, __shfl_xor(m, off, 8));
        float p = __expf(sc - m);
        float sum = p;
        for (int off = 1; off < 8; off <<= 1) sum += __shfl_xor(sum, off, 8);
        P[(size_t)t * 64 + lane] = p / sum;
    }
}

// ---------------------------------------------------------------------------
// Kernel 3: out = (P @ v) @ Wo' + bo, attnout never in LDS or HBM.
// (Verified round-3 kernel, unchanged.)
// ---------------------------------------------------------------------------
__global__ __launch_bounds__(256) void out_fused(
    const bf16* __restrict__ vb, const bf16* __restrict__ WoT,
    const float* __restrict__ P, const bf16* __restrict__ bob,
    float* __restrict__ outp)
{
    __shared__ bf16 Bs[2][256 * 64];   // 64 KB  Wo' chunk (double)
    __shared__ bf16 Vs[2][32 * 64];    // 8 KB   v chunk (double)
    int m0 = blockIdx.x * 32;
    int tid = threadIdx.x, wave = tid >> 6, lane = tid & 63;
    int wm = (wave >> 1) * 16, wn = (wave & 1) * 128;
    int mrow = lane & 15, quad = lane >> 4;
    int t = wm + mrow, ts = t & 7;
    int sl8 = lane >> 3, sl = lane & 7;

    float Pv[64];
    {
        const float* pr = P + (size_t)(m0 + t) * 64;
#pragma unroll
        for (int j = 0; j < 16; j++) {
            f32x4 v4 = *(const f32x4*)&pr[j * 4];
            Pv[4 * j + 0] = v4[0]; Pv[4 * j + 1] = v4[1];
            Pv[4 * j + 2] = v4[2]; Pv[4 * j + 3] = v4[3];
        }
    }

    f32x4 acc[8] = {};
    {   // prologue: stage chunk 0
        int tt = (wave << 3) + sl8;
        GLDS16(&vb[(size_t)(m0 + tt) * VN + ((sl ^ (tt & 7)) << 3)],
               &Vs[0][wave * 512]);
#pragma unroll
        for (int i = 0; i < 8; i++) {
            int n = (wave << 6) + (i << 3) + sl8;
            GLDS16(&WoT[(size_t)n * HD + ((sl ^ (n & 7)) << 3)],
                   &Bs[0][((wave << 6) + (i << 3)) << 6]);
        }
    }

    for (int c = 0; c < 32; c++) {
        __syncthreads();               // buf[c&1] resident (barrier drains vmcnt)
        if (c < 31) {
            int cc = c + 1, bb = cc & 1;
            int tt = (wave << 3) + sl8;
            GLDS16(&vb[(size_t)(m0 + tt) * VN + cc * 64 + ((sl ^ (tt & 7)) << 3)],
                   &Vs[bb][wave * 512]);
#pragma unroll
            for (int i = 0; i < 8; i++) {
                int n = (wave << 6) + (i << 3) + sl8;
                GLDS16(&WoT[(size_t)n * HD + cc * 64 + ((sl ^ (n & 7)) << 3)],
                       &Bs[bb][((wave << 6) + (i << 3)) << 6]);
            }
        }
        const bf16* Vb = Vs[c & 1];
        const bf16* Bb = Bs[c & 1];

        bf16x8 vf0 = *(const bf16x8*)&Vb[(t << 6) + ((quad ^ ts) << 3)];
        bf16x8 vf1 = *(const bf16x8*)&Vb[(t << 6) + (((quad + 4) ^ ts) << 3)];
        float v0f[8], v1f[8];
#pragma unroll
        for (int e = 0; e < 8; e++) { v0f[e] = (float)vf0[e]; v1f[e] = (float)vf1[e]; }
        bf16x8 af0, af1;
#pragma unroll
        for (int hh = 0; hh < 8; hh++) {
            float a0 = 0.f, a1 = 0.f;
#pragma unroll
            for (int gg = 0; gg < 8; gg++) {
                a0 += Pv[hh * 8 + gg] * v0f[gg];
                a1 += Pv[hh * 8 + gg] * v1f[gg];
            }
            af0[hh] = (bf16)a0; af1[hh] = (bf16)a1;
        }
#pragma unroll
        for (int nt = 0; nt < 8; nt++) {
            bf16x8 bv = *(const bf16x8*)&Bb[(wn + nt * 16 + mrow) * 64
                            + ((quad ^ (mrow & 7)) << 3)];
            acc[nt] = __builtin_amdgcn_mfma_f32_16x16x32_bf16(bv, af0, acc[nt], 0, 0, 0);
        }
#pragma unroll
        for (int nt = 0; nt < 8; nt++) {
            bf16x8 bv = *(const bf16x8*)&Bb[(wn + nt * 16 + mrow) * 64
                            + (((4 + quad) ^ (mrow & 7)) << 3)];
            acc[nt] = __builtin_amdgcn_mfma_f32_16x16x32_bf16(bv, af1, acc[nt], 0, 0, 0);
        }
    }

    int row = m0 + wm + mrow;
#pragma unroll
    for (int nt = 0; nt < 8; nt++) {
        int col = wn + nt * 16 + quad * 4;
        bf16x4 bb = *(const bf16x4*)&bob[col];
        f32x4 o;
        for (int r = 0; r < 4; r++) o[r] = acc[nt][r] + (float)bb[r];
        *(f32x4*)&outp[(size_t)row * D_ + col] = o;
    }
}

// ---------------------------------------------------------------------------
extern "C" void kernel_launch(void* const* d_in, const int* in_sizes, int n_in,
                              void* d_out, int out_size, void* d_ws, size_t ws_size,
                              hipStream_t stream)
{
    const void* x  = d_in[0];
    const void* Wq = d_in[1];
    const void* bq = d_in[2];
    const void* Wk = d_in[3];
    const void* bk = d_in[4];
    const void* Wv = d_in[5];
    const void* bv = d_in[6];
    const void* Wo = d_in[7];
    const void* bo = d_in[8];
    float* out = (float*)d_out;

    char* ws = (char*)d_ws;
    bf16*  vbuf = (bf16*)ws;                      // 16384*2048*2 = 67108864
    bf16*  WTI  = (bf16*)(ws + 67108864);         // 6144*256*2   = 3145728
    bf16*  WoT  = (bf16*)(ws + 70254592);         // 256*2048*2   = 1048576
    bf16*  xb   = (bf16*)(ws + 71303168);         // 16384*256*2  = 8388608
    bf16*  bqkv = (bf16*)(ws + 79691776);         // 6144*2       = 12288
    bf16*  bob  = (bf16*)(ws + 79704064);         // 512
    float* Pbuf = (float*)(ws + 79704576);        // 16384*64*4   = 4194304

    prep<<<6169, 256, 0, stream>>>(x, Wq, bq, Wk, bk, Wv, bv, Wo, bo,
                                   xb, WTI, WoT, bqkv, bob);
    qk_score<<<256, 512, 0, stream>>>(xb, WTI, bqkv, Pbuf);
    v_proj<<<dim3(16, 128), 256, 0, stream>>>(xb, WTI + 4096 * 256, bqkv + 4096, vbuf);
    out_fused<<<512, 256, 0, stream>>>(vbuf, WoT, Pbuf, bob, out);
}